// Round 1
// baseline (479.155 us; speedup 1.0000x reference)
//
#include <hip/hip_runtime.h>

// EpistemicQuantizer — primal-only:
//   out0 = codebook[argmax_j (x . cbn_j)]  (raw codebook rows)
//   out1 = argmax indices (as float32 values; harness reads whole out buf as f32)
// gumbel_noise input is numerically dead for the primal outputs -> never read.

constexpr int N_ROWS = 16384;   // B*T
constexpr int D      = 64;
constexpr int V      = 4096;
constexpr int BM     = 64;      // rows per block
constexpr int BV     = 128;     // codes per LDS tile
constexpr int LS     = 68;      // padded LDS row stride (floats), 16B-aligned pad
constexpr int NT     = V / BV;  // 32 tiles

__global__ void normalize_cb(const float* __restrict__ cb, float* __restrict__ cbn) {
    int row = blockIdx.x * blockDim.x + threadIdx.x;
    if (row >= V) return;
    const float4* src = reinterpret_cast<const float4*>(cb + row * D);
    float4 v[16];
    float ss = 0.f;
#pragma unroll
    for (int i = 0; i < 16; ++i) {
        v[i] = src[i];
        ss += v[i].x * v[i].x + v[i].y * v[i].y + v[i].z * v[i].z + v[i].w * v[i].w;
    }
    float inv = 1.0f / fmaxf(sqrtf(ss), 1e-12f);
    float4* dst = reinterpret_cast<float4*>(cbn + row * D);
#pragma unroll
    for (int i = 0; i < 16; ++i)
        dst[i] = make_float4(v[i].x * inv, v[i].y * inv, v[i].z * inv, v[i].w * inv);
}

__global__ __launch_bounds__(256) void quantize(const float* __restrict__ x,
                                                const float* __restrict__ cb,
                                                const float* __restrict__ cbn,
                                                float* __restrict__ out) {
    __shared__ float xs[BM * LS];   // 64 x 68 floats = 17408 B
    __shared__ float bs[BV * LS];   // 128 x 68 floats = 34816 B
    const int tid = threadIdx.x;
    const int tc = tid & 15;        // code-group 0..15
    const int tr = tid >> 4;        // row-group 0..15
    const int row0 = blockIdx.x * BM;

    // stage x tile: 64 rows x 64 floats, contiguous in global
#pragma unroll
    for (int p = 0; p < 4; ++p) {
        int flat = p * 1024 + tid * 4;
        int r = flat >> 6, k = flat & 63;
        float4 v = *reinterpret_cast<const float4*>(x + row0 * D + flat);
        *reinterpret_cast<float4*>(&xs[r * LS + k]) = v;
    }

    float best_v[4];
    int   best_i[4];
#pragma unroll
    for (int m = 0; m < 4; ++m) { best_v[m] = -1e30f; best_i[m] = 0; }

    for (int t = 0; t < NT; ++t) {
        __syncthreads();  // protect bs from previous tile's readers (and xs staging on t==0)
#pragma unroll
        for (int p = 0; p < 8; ++p) {
            int flat = p * 1024 + tid * 4;
            int r = flat >> 6, k = flat & 63;
            float4 v = *reinterpret_cast<const float4*>(cbn + t * BV * D + flat);
            *reinterpret_cast<float4*>(&bs[r * LS + k]) = v;
        }
        __syncthreads();

        float acc[4][8];
#pragma unroll
        for (int m = 0; m < 4; ++m)
#pragma unroll
            for (int n = 0; n < 8; ++n) acc[m][n] = 0.f;

#pragma unroll
        for (int kk = 0; kk < D; kk += 4) {
            float4 a[4], b[8];
#pragma unroll
            for (int m = 0; m < 4; ++m)
                a[m] = *reinterpret_cast<const float4*>(&xs[(tr + 16 * m) * LS + kk]);
#pragma unroll
            for (int n = 0; n < 8; ++n)
                b[n] = *reinterpret_cast<const float4*>(&bs[(tc + 16 * n) * LS + kk]);
#pragma unroll
            for (int m = 0; m < 4; ++m)
#pragma unroll
                for (int n = 0; n < 8; ++n) {
                    acc[m][n] = fmaf(a[m].x, b[n].x, acc[m][n]);
                    acc[m][n] = fmaf(a[m].y, b[n].y, acc[m][n]);
                    acc[m][n] = fmaf(a[m].z, b[n].z, acc[m][n]);
                    acc[m][n] = fmaf(a[m].w, b[n].w, acc[m][n]);
                }
        }

        // running best; codes ascend with t and n, strict '>' keeps lowest index
#pragma unroll
        for (int m = 0; m < 4; ++m)
#pragma unroll
            for (int n = 0; n < 8; ++n) {
                int code = t * BV + tc + 16 * n;
                if (acc[m][n] > best_v[m]) { best_v[m] = acc[m][n]; best_i[m] = code; }
            }
    }

    // cross-thread argmax reduction over the 16 column-groups (stride 17 avoids conflicts)
    __syncthreads();
    float* rv = bs;                                   // [BM][17]
    int*   ri = reinterpret_cast<int*>(bs + BM * 17); // [BM][17]
#pragma unroll
    for (int m = 0; m < 4; ++m) {
        int row = tr + 16 * m;
        rv[row * 17 + tc] = best_v[m];
        ri[row * 17 + tc] = best_i[m];
    }
    int* fin = reinterpret_cast<int*>(xs);
    __syncthreads();
    if (tid < BM) {
        float bv = rv[tid * 17];
        int   bi = ri[tid * 17];
#pragma unroll
        for (int c = 1; c < 16; ++c) {
            float v = rv[tid * 17 + c];
            int   i = ri[tid * 17 + c];
            if (v > bv || (v == bv && i < bi)) { bv = v; bi = i; }  // np.argmax: first max wins
        }
        fin[tid] = bi;
        out[N_ROWS * D + row0 + tid] = (float)bi;     // indices as float32 values
    }
    __syncthreads();

    // gather raw codebook rows -> z output (4 threads per row, 16 floats each)
    {
        int row = tid >> 2, part = tid & 3;
        const float4* src = reinterpret_cast<const float4*>(cb + fin[row] * D) + part * 4;
        float4*       dst = reinterpret_cast<float4*>(out + (row0 + row) * D) + part * 4;
#pragma unroll
        for (int i = 0; i < 4; ++i) dst[i] = src[i];
    }
}

extern "C" void kernel_launch(void* const* d_in, const int* in_sizes, int n_in,
                              void* d_out, int out_size, void* d_ws, size_t ws_size,
                              hipStream_t stream) {
    const float* x   = (const float*)d_in[0];
    const float* cb  = (const float*)d_in[1];
    // d_in[2] (gumbel_noise) intentionally unused: dead for primal outputs
    float* cbn = (float*)d_ws;          // 4096*64 floats = 1 MB scratch
    float* out = (float*)d_out;

    normalize_cb<<<V / 256, 256, 0, stream>>>(cb, cbn);
    quantize<<<N_ROWS / BM, 256, 0, stream>>>(x, cb, cbn, out);
}

// Round 2
// 429.795 us; speedup vs baseline: 1.1148x; 1.1148x over previous
//
#include <hip/hip_runtime.h>

// EpistemicQuantizer — primal-only:
//   out0 = codebook[argmax_j (x . cbn_j)]  (raw codebook rows)
//   out1 = argmax indices (as float32 values)
// gumbel_noise input is numerically dead for the primal outputs -> never read.
//
// V split across 4 chunks so grid = 1024 blocks (3 resident/CU with 52KB LDS);
// partial per-row (val,idx) merged by a small second kernel.

constexpr int N_ROWS = 16384;     // B*T
constexpr int D      = 64;
constexpr int V      = 4096;
constexpr int BM     = 64;        // rows per block
constexpr int BN     = 128;       // codes per LDS tile
constexpr int NCH    = 4;         // V chunks
constexpr int VCHUNK = V / NCH;   // 1024
constexpr int NT     = VCHUNK / BN; // 8 tiles per block
constexpr int LS     = 68;        // padded LDS row stride (floats), 16B-aligned

__global__ __launch_bounds__(256) void normalize_cb(const float* __restrict__ cb,
                                                    float* __restrict__ cbn) {
    int g = blockIdx.x * 256 + threadIdx.x;   // 65536 threads: 16 per row
    int row = g >> 4, part = g & 15;
    float4 v = *reinterpret_cast<const float4*>(cb + row * D + part * 4);
    float ss = v.x * v.x + v.y * v.y + v.z * v.z + v.w * v.w;
    ss += __shfl_xor(ss, 1);
    ss += __shfl_xor(ss, 2);
    ss += __shfl_xor(ss, 4);
    ss += __shfl_xor(ss, 8);
    float inv = 1.0f / fmaxf(sqrtf(ss), 1e-12f);
    *reinterpret_cast<float4*>(cbn + row * D + part * 4) =
        make_float4(v.x * inv, v.y * inv, v.z * inv, v.w * inv);
}

__global__ __launch_bounds__(256, 3) void quantize(const float* __restrict__ x,
                                                   const float* __restrict__ cbn,
                                                   float* __restrict__ pv,
                                                   int* __restrict__ pi) {
    __shared__ float xs[BM * LS];   // 64 x 68 floats = 17408 B
    __shared__ float bs[BN * LS];   // 128 x 68 floats = 34816 B  (total 52224 B -> 3 blocks/CU)
    const int tid = threadIdx.x;
    const int tc = tid & 15;        // code-group 0..15
    const int tr = tid >> 4;        // row-group 0..15
    const int rowblk = blockIdx.x & (N_ROWS / BM - 1);  // 0..255
    const int chunk  = blockIdx.x >> 8;                 // 0..3
    const int row0  = rowblk * BM;
    const int vbase = chunk * VCHUNK;

    // stage x tile: 64 rows x 64 floats (1024 float4), coalesced
#pragma unroll
    for (int p = 0; p < 4; ++p) {
        int f = p * 256 + tid;
        int r = f >> 4, k4 = f & 15;
        float4 v = *reinterpret_cast<const float4*>(x + row0 * D + f * 4);
        *reinterpret_cast<float4*>(&xs[r * LS + k4 * 4]) = v;
    }

    float best_v[4];
    int   best_i[4];
#pragma unroll
    for (int m = 0; m < 4; ++m) { best_v[m] = -1e30f; best_i[m] = 0; }

    for (int t = 0; t < NT; ++t) {
        __syncthreads();  // protect bs from previous tile's readers (t==0: xs staging)
#pragma unroll
        for (int p = 0; p < 8; ++p) {
            int f = p * 256 + tid;
            int r = f >> 4, k4 = f & 15;
            float4 v = *reinterpret_cast<const float4*>(cbn + (vbase + t * BN) * D + f * 4);
            *reinterpret_cast<float4*>(&bs[r * LS + k4 * 4]) = v;
        }
        __syncthreads();

        float acc[4][8];
#pragma unroll
        for (int m = 0; m < 4; ++m)
#pragma unroll
            for (int n = 0; n < 8; ++n) acc[m][n] = 0.f;

#pragma unroll
        for (int kk = 0; kk < D; kk += 4) {
            float4 a[4], b[8];
#pragma unroll
            for (int m = 0; m < 4; ++m)
                a[m] = *reinterpret_cast<const float4*>(&xs[(tr + 16 * m) * LS + kk]);
#pragma unroll
            for (int n = 0; n < 8; ++n)
                b[n] = *reinterpret_cast<const float4*>(&bs[(tc + 16 * n) * LS + kk]);
#pragma unroll
            for (int m = 0; m < 4; ++m)
#pragma unroll
                for (int n = 0; n < 8; ++n) {
                    acc[m][n] = fmaf(a[m].x, b[n].x, acc[m][n]);
                    acc[m][n] = fmaf(a[m].y, b[n].y, acc[m][n]);
                    acc[m][n] = fmaf(a[m].z, b[n].z, acc[m][n]);
                    acc[m][n] = fmaf(a[m].w, b[n].w, acc[m][n]);
                }
        }

        // running best; codes ascend with t and n, strict '>' keeps lowest index
#pragma unroll
        for (int m = 0; m < 4; ++m)
#pragma unroll
            for (int n = 0; n < 8; ++n) {
                int code = vbase + t * BN + tc + 16 * n;
                if (acc[m][n] > best_v[m]) { best_v[m] = acc[m][n]; best_i[m] = code; }
            }
    }

    // cross-thread argmax over the 16 column-groups (stride 17 avoids conflicts)
    __syncthreads();
    float* rv = xs;                                   // [64][17] = 4352 floats
    int*   ri = reinterpret_cast<int*>(xs + BM * 17); // [64][17]
#pragma unroll
    for (int m = 0; m < 4; ++m) {
        int row = tr + 16 * m;
        rv[row * 17 + tc] = best_v[m];
        ri[row * 17 + tc] = best_i[m];
    }
    __syncthreads();
    if (tid < BM) {
        float bv = rv[tid * 17];
        int   bi = ri[tid * 17];
#pragma unroll
        for (int c = 1; c < 16; ++c) {
            float v = rv[tid * 17 + c];
            int   i = ri[tid * 17 + c];
            if (v > bv || (v == bv && i < bi)) { bv = v; bi = i; }  // first max wins
        }
        pv[chunk * N_ROWS + row0 + tid] = bv;
        pi[chunk * N_ROWS + row0 + tid] = bi;
    }
}

__global__ __launch_bounds__(256) void merge_gather(const float* __restrict__ pv,
                                                    const int* __restrict__ pi,
                                                    const float* __restrict__ cb,
                                                    float* __restrict__ out) {
    int g = blockIdx.x * 256 + threadIdx.x;   // 4 threads per row
    int row = g >> 2, q = g & 3;
    float bv = pv[row];
    int   bi = pi[row];
#pragma unroll
    for (int c = 1; c < NCH; ++c) {
        float v = pv[c * N_ROWS + row];
        int   i = pi[c * N_ROWS + row];
        if (v > bv) { bv = v; bi = i; }  // ascending chunks: strict '>' keeps lowest index
    }
    if (q == 0) out[N_ROWS * D + row] = (float)bi;   // index as float32 value
    const float4* src = reinterpret_cast<const float4*>(cb + bi * D) + q * 4;
    float4*       dst = reinterpret_cast<float4*>(out + row * D) + q * 4;
#pragma unroll
    for (int i = 0; i < 4; ++i) dst[i] = src[i];
}

extern "C" void kernel_launch(void* const* d_in, const int* in_sizes, int n_in,
                              void* d_out, int out_size, void* d_ws, size_t ws_size,
                              hipStream_t stream) {
    const float* x  = (const float*)d_in[0];
    const float* cb = (const float*)d_in[1];
    // d_in[2] (gumbel_noise) intentionally unused: dead for primal outputs
    float* cbn = (float*)d_ws;                                        // 1 MB
    float* pv  = (float*)((char*)d_ws + (size_t)V * D * 4);           // 256 KB
    int*   pi  = (int*)  ((char*)d_ws + (size_t)V * D * 4
                                      + (size_t)NCH * N_ROWS * 4);    // 256 KB
    float* out = (float*)d_out;

    normalize_cb<<<V * 16 / 256, 256, 0, stream>>>(cb, cbn);
    quantize<<<(N_ROWS / BM) * NCH, 256, 0, stream>>>(x, cbn, pv, pi);
    merge_gather<<<N_ROWS * 4 / 256, 256, 0, stream>>>(pv, pi, cb, out);
}